// Round 9
// baseline (231.206 us; speedup 1.0000x reference)
//
#include <hip/hip_runtime.h>
#include <math.h>

typedef unsigned short ushort;
typedef unsigned int uint;
typedef __attribute__((ext_vector_type(8))) short bf16x8;
typedef __attribute__((ext_vector_type(8))) ushort ushort8;
typedef __attribute__((ext_vector_type(4))) float f32x4;

// ws layout (float offsets)
#define WT1_OFF   0          // 200 f   conv1 weights [tap][co]
#define MV_OFF    256        // 1152 f  mask vector
#define BIAS_OFF  1536       // 48 f    padded biases (conv2/3/4)
#define BFH_OFF   1600       // hi B-frags (3 convs): 3*7*64*8 ushort = 5376 f
#define BFL_OFF   6976       // lo B-frags: 5376 f
#define BFP_OFF   12352      // packed [bh|bl] B-frags for conv3/4: 2*448*8 ush = 3584 f
#define BUFA_OFF  16384      // activation buffer A: hi plane + lo plane
#define PLANE_U   9437184    // ushorts per plane (256*48*96*8)
#define BUFB_OFF  (BUFA_OFF + PLANE_U)
#define PART2_OFF (BUFB_OFF + PLANE_U)        // 48*256 f (atomic partials)

__device__ __forceinline__ ushort f2bf(float f) {      // RTNE fp32->bf16
    union { float f; uint u; } a; a.f = f;
    uint u = a.u;
    return (ushort)((u + 0x7FFFu + ((u >> 16) & 1u)) >> 16);
}
__device__ __forceinline__ float bf2f(ushort s) {
    union { uint u; float f; } a; a.u = ((uint)s) << 16; return a.f;
}
__device__ __forceinline__ void split_bf(float v, ushort& h, ushort& l) {
    h = f2bf(v);
    l = f2bf(v - bf2f(h));
}

// ---------------- K0: weights/mask/bias/B-frag precompute + part2 zero ---
__global__ void prep_kernel(const float* __restrict__ c1w, const float* __restrict__ c2w,
                            const float* __restrict__ c3w, const float* __restrict__ c4w,
                            const float* __restrict__ c2b, const float* __restrict__ c3b,
                            const float* __restrict__ c4b,
                            const float* __restrict__ mask, float* __restrict__ ws) {
    int idx = blockIdx.x * blockDim.x + threadIdx.x;
    if (idx < 200) {                       // conv1 weights -> [tap][co]
        int co = idx & 7, rest = idx >> 3;
        int dx = rest % 5, dy = rest / 5;
        ws[WT1_OFF + idx] = c1w[co * 25 + dy * 5 + dx];
    }
    if (idx < 1152) {
        int i = idx / 48, j = idx % 48;
        ws[MV_OFF + idx] = (mask[i * 8 * 384 + j * 8] > 0.5f) ? 1.0f : 0.0f;
    }
    if (idx < 48) {                        // padded biases
        int c = idx >> 4, co = idx & 15;
        const float* b = (c == 0) ? c2b : (c == 1) ? c3b : c4b;
        ws[BIAS_OFF + idx] = (co < 8) ? b[co] : 0.f;
    }
    if (idx < 1344) {                      // separate hi/lo B-frags (k1 uses conv2's)
        int c = idx / 448, rem = idx % 448;
        int g = rem >> 6, l = rem & 63;
        int tg = l >> 4, co16 = l & 15;
        int tap = g * 4 + tg;
        const float* wsrc = (c == 0) ? c2w : (c == 1) ? c3w : c4w;
        ushort* bh = (ushort*)(ws + BFH_OFF) + (size_t)idx * 8;
        ushort* bl = (ushort*)(ws + BFL_OFF) + (size_t)idx * 8;
#pragma unroll
        for (int j = 0; j < 8; ++j) {      // j = ci
            float v = 0.f;
            if (tap < 25 && co16 < 8)
                v = wsrc[((co16 * 8 + j) * 5 + tap / 5) * 5 + (tap % 5)];
            ushort h, lo; split_bf(v, h, lo);
            bh[j] = h; bl[j] = lo;
        }
    }
    if (idx < 896) {                       // packed [bh|bl] frags for conv3/conv4
        int c = idx / 448 + 1, rem = idx % 448;
        int g = rem >> 6, l = rem & 63;
        int tg = l >> 4, co16 = l & 15;
        int co = co16 & 7;
        int tap = g * 4 + tg;
        const float* wsrc = (c == 1) ? c3w : c4w;
        ushort* dst = (ushort*)(ws + BFP_OFF) + (size_t)idx * 8;
#pragma unroll
        for (int j = 0; j < 8; ++j) {
            float v = 0.f;
            if (tap < 25)
                v = wsrc[((co * 8 + j) * 5 + tap / 5) * 5 + (tap % 5)];
            ushort h, lo; split_bf(v, h, lo);
            dst[j] = (co16 < 8) ? h : lo;
        }
    }
    if (idx < 48 * 256)                    // zero atomic partial buffer
        ws[PART2_OFF + idx] = 0.f;
}

// ---------------- K1: ds + conv1(VALU) + conv2(3-MFMA split) + relu + pool
// Tile: 16 conv2-rows x 64 cols -> pooled 8x32. 4 waves; wave w rows 4w..4w+3.
// LDS 51.7 KB -> 3 blocks/CU (xdbuf overlaid with pooled bounce buffers).
__global__ __launch_bounds__(256) void k1_fused(
        const float* __restrict__ x, const float* __restrict__ wt1,
        const float* __restrict__ c1b,
        const ushort* __restrict__ bfh, const ushort* __restrict__ bfl,
        const float* __restrict__ biaspad, ushort* __restrict__ z2) {
    __shared__ __align__(16) char smem0[8192];          // xdbuf | z2 bounce
    __shared__ ushort z1h[20 * 68 * 8];                 // 21,760 B
    __shared__ ushort z1l[20 * 68 * 8];                 // 21,760 B
    float (*xdbuf)[72] = reinterpret_cast<float(*)[72]>(smem0);   // 24x72 f32
    ushort* z2bh = (ushort*)smem0;                      // 8x32x8 (xdbuf dead by then)
    ushort* z2bl = (ushort*)(smem0 + 4096);
    const int rt = blockIdx.x, ct = blockIdx.y, b = blockIdx.z;
    const int tid = threadIdx.x;
    const int ry0 = rt * 16, cx0 = ct * 64;

    // phase 0: 2x2 avg downsample into xdbuf (fp32)
    for (int i = tid; i < 24 * 36; i += 256) {
        int pr = i / 36, pj = i % 36;
        int gy = ry0 - 4 + pr, gx = cx0 - 4 + 2 * pj;
        float v0 = 0.f, v1 = 0.f;
        if (gy >= 0 && gy < 96 && gx >= 0 && gx < 192) {
            const float* p = x + (size_t)b * (192 * 384) + (2 * gy) * 384 + 2 * gx;
            float4 a = *(const float4*)p;
            float4 c = *(const float4*)(p + 384);
            v0 = (a.x + a.y + c.x + c.y) * 0.25f;
            v1 = (a.z + a.w + c.z + c.w) * 0.25f;
        }
        xdbuf[pr][2 * pj]     = v0;
        xdbuf[pr][2 * pj + 1] = v1;
    }
    __syncthreads();

    // phase 1: conv1 -> split bf16 z1 planes. 4-row vertical strips: thread
    // owns px (iy0..iy0+3, c); 8x5 window shared -> 10 b32 reads/px (was 25).
    // Writes keep the r7 lane-stride-16B pattern (no r6-style 32-way conflict).
    for (int s = tid; s < 5 * 68; s += 256) {
        int rg = s / 68, c = s % 68;
        const int iy0 = rg * 4;
        float acc[4][8];
#pragma unroll
        for (int k = 0; k < 4; ++k)
#pragma unroll
            for (int co = 0; co < 8; ++co) acc[k][co] = c1b[co];
#pragma unroll
        for (int ry = 0; ry < 8; ++ry) {
            float wv[5];
#pragma unroll
            for (int dx = 0; dx < 5; ++dx) wv[dx] = xdbuf[iy0 + ry][c + dx];
#pragma unroll
            for (int k = 0; k < 4; ++k) {
                if (k >= ry - 4 && k <= ry && ry - k < 5) {   // dy in [0,4]
                    const int dy = ry - k;
                    const float* wp = wt1 + dy * 5 * 8;
#pragma unroll
                    for (int dx = 0; dx < 5; ++dx)
#pragma unroll
                        for (int co = 0; co < 8; ++co)
                            acc[k][co] = fmaf(wv[dx], wp[dx * 8 + co], acc[k][co]);
                }
            }
        }
#pragma unroll
        for (int k = 0; k < 4; ++k) {
            const int iy = iy0 + k;
            const int gy = ry0 - 2 + iy, gx = cx0 - 2 + c;
            const bool ok = (gy >= 0 && gy < 96 && gx >= 0 && gx < 192);
            ushort8 uh, ul;
#pragma unroll
            for (int co = 0; co < 8; ++co) {
                float v = ok ? acc[k][co] : 0.f;
                ushort h, lo; split_bf(v, h, lo);
                uh[co] = h; ul[co] = lo;
            }
            const int pix = iy * 68 + c;
            *(ushort8*)&z1h[pix * 8] = uh;
            *(ushort8*)&z1l[pix * 8] = ul;
        }
    }
    __syncthreads();

    // phase 2: conv2 via 3-term split MFMA (all into one acc), + bias, relu, pool
    const int lane = tid & 63, w = tid >> 6;
    const int p = lane & 15, tg = lane >> 4;
    bf16x8 bwh[7], bwl[7];
#pragma unroll
    for (int g = 0; g < 7; ++g) {
        bwh[g] = *(const bf16x8*)(bfh + (size_t)(g * 64 + lane) * 8);
        bwl[g] = *(const bf16x8*)(bfl + (size_t)(g * 64 + lane) * 8);
    }
    const float bias = biaspad[lane & 15];
    int off[7];
#pragma unroll
    for (int g = 0; g < 7; ++g) {
        int t = g * 4 + tg; t = (t > 24) ? 24 : t;   // pad taps: zero weights
        off[g] = ((t / 5) * 68 + (t % 5)) * 8;
    }
    float stash[4][2];
#pragma unroll
    for (int rl = 0; rl < 4; ++rl) {
        const int r = 4 * w + rl;
#pragma unroll
        for (int cg = 0; cg < 4; ++cg) {
            f32x4 acc = {0.f, 0.f, 0.f, 0.f};
            const int base = (r * 68 + cg * 16 + p) * 8;
#pragma unroll
            for (int g = 0; g < 7; ++g) {
                bf16x8 ah = *(const bf16x8*)&z1h[base + off[g]];
                bf16x8 al = *(const bf16x8*)&z1l[base + off[g]];
                acc = __builtin_amdgcn_mfma_f32_16x16x32_bf16(ah, bwh[g], acc, 0, 0, 0);
                acc = __builtin_amdgcn_mfma_f32_16x16x32_bf16(ah, bwl[g], acc, 0, 0, 0);
                acc = __builtin_amdgcn_mfma_f32_16x16x32_bf16(al, bwh[g], acc, 0, 0, 0);
            }
            // C: col(lane&15)=co, row=tg*4+i=pixel. relu(max) + col-pair pool
            float p0 = fmaxf(fmaxf(acc[0], acc[1]) + bias, 0.f);
            float p1 = fmaxf(fmaxf(acc[2], acc[3]) + bias, 0.f);
            if ((rl & 1) == 0) {
                stash[cg][0] = p0; stash[cg][1] = p1;
            } else {
                p0 = fmaxf(p0, stash[cg][0]);
                p1 = fmaxf(p1, stash[cg][1]);
                if ((lane & 15) < 8) {
                    int pr = 2 * w + (rl >> 1);
                    int pc = cg * 8 + tg * 2;
                    ushort h0, l0, h1, l1;
                    split_bf(p0, h0, l0); split_bf(p1, h1, l1);
                    z2bh[(pr * 32 + pc) * 8 + (lane & 15)]     = h0;
                    z2bl[(pr * 32 + pc) * 8 + (lane & 15)]     = l0;
                    z2bh[(pr * 32 + pc + 1) * 8 + (lane & 15)] = h1;
                    z2bl[(pr * 32 + pc + 1) * 8 + (lane & 15)] = l1;
                }
            }
        }
    }
    __syncthreads();
    // cooperative pooled-tile store (8x32 px, 16B per plane)
    {
        int prr = tid >> 5, pcc = tid & 31;
        size_t gidx = ((size_t)(b * 48 + rt * 8 + prr) * 96 + ct * 32 + pcc) * 8;
        *(ushort8*)(z2 + gidx)           = *(const ushort8*)&z2bh[(prr * 32 + pcc) * 8];
        *(ushort8*)(z2 + PLANE_U + gidx) = *(const ushort8*)&z2bl[(prr * 32 + pcc) * 8];
    }
}

// ---------------- K2/K3: 8->8 conv via N-packed split MFMA ---------------
// Tile: 16 rows x 32 cols. LDS 39.4 KB -> 4 blocks/CU.
__global__ __launch_bounds__(256) void conv_mfma(
        const ushort* __restrict__ in, ushort* __restrict__ out,
        const ushort* __restrict__ bfrag, const float* __restrict__ biaspad,
        int do_relu) {
    __shared__ ushort inh[20 * 36 * 8];       // 11,520 B
    __shared__ ushort inl[20 * 36 * 8];       // 11,520 B
    __shared__ ushort outh[16 * 32 * 8];      // 8,192 B
    __shared__ ushort outl[16 * 32 * 8];      // 8,192 B
    const int rt = blockIdx.x, ctile = blockIdx.y, b = blockIdx.z;
    const int ry0 = rt * 16, cx0 = ctile * 32;
    const int tid = threadIdx.x;

    // stage 20x36 px (16B per plane), zero-padded
    for (int u = tid; u < 20 * 36; u += 256) {
        int r = u / 36, col = u % 36;
        int gy = ry0 - 2 + r, gc = cx0 - 2 + col;
        ushort8 vh = {0, 0, 0, 0, 0, 0, 0, 0};
        ushort8 vl = vh;
        if (gy >= 0 && gy < 48 && gc >= 0 && gc < 96) {
            size_t gidx = ((size_t)(b * 48 + gy) * 96 + gc) * 8;
            vh = *(const ushort8*)(in + gidx);
            vl = *(const ushort8*)(in + PLANE_U + gidx);
        }
        *(ushort8*)&inh[u * 8] = vh;
        *(ushort8*)&inl[u * 8] = vl;
    }
    __syncthreads();

    const int lane = tid & 63, w = tid >> 6;
    const int p = lane & 15, tg = lane >> 4;
    bf16x8 bw[7];
#pragma unroll
    for (int g = 0; g < 7; ++g)
        bw[g] = *(const bf16x8*)(bfrag + (size_t)(g * 64 + lane) * 8);
    const float bias = biaspad[lane & 15];
    int off[7];
#pragma unroll
    for (int g = 0; g < 7; ++g) {
        int t = g * 4 + tg; t = (t > 24) ? 24 : t;
        off[g] = ((t / 5) * 36 + (t % 5)) * 8;
    }
#pragma unroll
    for (int rl = 0; rl < 4; ++rl) {
        const int r = 4 * w + rl;
#pragma unroll
        for (int cg = 0; cg < 2; ++cg) {
            f32x4 a1 = {0.f, 0.f, 0.f, 0.f};
            f32x4 a2 = {0.f, 0.f, 0.f, 0.f};
            const int base = (r * 36 + cg * 16 + p) * 8;
#pragma unroll
            for (int g = 0; g < 7; ++g) {
                bf16x8 ah = *(const bf16x8*)&inh[base + off[g]];
                bf16x8 al = *(const bf16x8*)&inl[base + off[g]];
                a1 = __builtin_amdgcn_mfma_f32_16x16x32_bf16(ah, bw[g], a1, 0, 0, 0);
                a2 = __builtin_amdgcn_mfma_f32_16x16x32_bf16(al, bw[g], a2, 0, 0, 0);
            }
            f32x4 s = a1 + a2;
            float tot[4];
#pragma unroll
            for (int i = 0; i < 4; ++i)
                tot[i] = s[i] + __shfl_xor(s[i], 8);
            if ((lane & 15) < 8) {
#pragma unroll
                for (int i = 0; i < 4; ++i) {
                    float v = tot[i] + bias;
                    if (do_relu) v = fmaxf(v, 0.f);
                    int px = r * 32 + cg * 16 + tg * 4 + i;
                    ushort h, lo; split_bf(v, h, lo);
                    outh[px * 8 + (lane & 15)] = h;
                    outl[px * 8 + (lane & 15)] = lo;
                }
            }
        }
    }
    __syncthreads();
    for (int u = tid; u < 16 * 32; u += 256) {
        int row = u / 32, col = u % 32;
        size_t gidx = ((size_t)(b * 48 + ry0 + row) * 96 + cx0 + col) * 8;
        *(ushort8*)(out + gidx)           = *(const ushort8*)&outh[u * 8];
        *(ushort8*)(out + PLANE_U + gidx) = *(const ushort8*)&outl[u * 8];
    }
}

// ---------------- K4: per-feature MLP; atomic partial into part2 ---------
__global__ __launch_bounds__(256) void mlp_kernel(
        const ushort* __restrict__ z4, const float* __restrict__ W1,
        const float* __restrict__ b1, const float* __restrict__ W2,
        const float* __restrict__ b2, const float* __restrict__ W3,
        const float* __restrict__ mv, float* __restrict__ part2) {
    const int f = blockIdx.x;
    const int bb = threadIdx.x;
    if (mv[f] == 0.f) return;
    const int y = f / 48, xcol = f % 48;
    size_t s0i = (((size_t)bb * 48 + 2 * y) * 96 + 2 * xcol) * 8;
    ushort8 ah0 = *(const ushort8*)(z4 + s0i);
    ushort8 ah1 = *(const ushort8*)(z4 + s0i + 8);
    ushort8 ch0 = *(const ushort8*)(z4 + s0i + 96 * 8);
    ushort8 ch1 = *(const ushort8*)(z4 + s0i + 96 * 8 + 8);
    ushort8 al0 = *(const ushort8*)(z4 + PLANE_U + s0i);
    ushort8 al1 = *(const ushort8*)(z4 + PLANE_U + s0i + 8);
    ushort8 cl0 = *(const ushort8*)(z4 + PLANE_U + s0i + 96 * 8);
    ushort8 cl1 = *(const ushort8*)(z4 + PLANE_U + s0i + 96 * 8 + 8);
    float h[8];
#pragma unroll
    for (int c = 0; c < 8; ++c) {
        float v00 = bf2f(ah0[c]) + bf2f(al0[c]);
        float v01 = bf2f(ah1[c]) + bf2f(al1[c]);
        float v10 = bf2f(ch0[c]) + bf2f(cl0[c]);
        float v11 = bf2f(ch1[c]) + bf2f(cl1[c]);
        h[c] = fmaxf(fmaxf(v00, v01), fmaxf(v10, v11));
    }

    const float* w1p = W1 + (size_t)f * 8 * 32;
    const float* b1p = b1 + (size_t)f * 32;
    float t1[32];
#pragma unroll
    for (int j = 0; j < 32; ++j) t1[j] = b1p[j];
    for (int c = 0; c < 8; ++c) {
        float hv = h[c];
        const float* wp = w1p + c * 32;
#pragma unroll
        for (int j = 0; j < 32; ++j) t1[j] = fmaf(hv, wp[j], t1[j]);
    }
#pragma unroll
    for (int j = 0; j < 32; ++j) t1[j] = fmaxf(t1[j], 0.f);

    const float* w2p = W2 + (size_t)f * 32 * 32;
    const float* b2p = b2 + (size_t)f * 32;
    float t2[32];
#pragma unroll
    for (int g = 0; g < 32; ++g) t2[g] = b2p[g];
    for (int j = 0; j < 32; ++j) {
        float tv = t1[j];
        const float* wp = w2p + j * 32;
#pragma unroll
        for (int g = 0; g < 32; ++g) t2[g] = fmaf(tv, wp[g], t2[g]);
    }
    const float* w3p = W3 + (size_t)f * 32;
    float s = 0.f;
#pragma unroll
    for (int g = 0; g < 32; ++g) s = fmaf(fmaxf(t2[g], 0.f), w3p[g], s);
    atomicAdd(&part2[(size_t)(f / 24) * 256 + bb], s);
}

// ---------------- K5: final reduce + bias + sigmoid ----------------------
__global__ void reduce2_kernel(const float* __restrict__ part2, const float* __restrict__ ab,
                               float* __restrict__ out) {
    int bb = threadIdx.x;
    float s = 0.f;
    for (int k = 0; k < 48; ++k) s += part2[(size_t)k * 256 + bb];
    s += ab[0];
    out[bb] = 1.f / (1.f + expf(-s));
}

extern "C" void kernel_launch(void* const* d_in, const int* in_sizes, int n_in,
                              void* d_out, int out_size, void* d_ws, size_t ws_size,
                              hipStream_t stream) {
    const float* x    = (const float*)d_in[0];
    const float* mask = (const float*)d_in[1];
    const float* c1w  = (const float*)d_in[2];
    const float* c1b  = (const float*)d_in[3];
    const float* c2w  = (const float*)d_in[4];
    const float* c2b  = (const float*)d_in[5];
    const float* c3w  = (const float*)d_in[6];
    const float* c3b  = (const float*)d_in[7];
    const float* c4w  = (const float*)d_in[8];
    const float* c4b  = (const float*)d_in[9];
    const float* W1   = (const float*)d_in[10];
    const float* b1   = (const float*)d_in[11];
    const float* W2   = (const float*)d_in[12];
    const float* b2   = (const float*)d_in[13];
    const float* W3   = (const float*)d_in[14];
    const float* ab   = (const float*)d_in[15];
    float* ws = (float*)d_ws;

    float*  wt1   = ws + WT1_OFF;
    float*  mv    = ws + MV_OFF;
    float*  biasp = ws + BIAS_OFF;
    ushort* bfh   = (ushort*)(ws + BFH_OFF);
    ushort* bfl   = (ushort*)(ws + BFL_OFF);
    ushort* bfp   = (ushort*)(ws + BFP_OFF);
    ushort* bufA  = (ushort*)(ws + BUFA_OFF);  // z2, later z4
    ushort* bufB  = (ushort*)(ws + BUFB_OFF);  // z3
    float*  part2 = ws + PART2_OFF;

    prep_kernel<<<48, 256, 0, stream>>>(c1w, c2w, c3w, c4w, c2b, c3b, c4b, mask, ws);
    k1_fused<<<dim3(6, 3, 256), 256, 0, stream>>>(x, wt1, c1b, bfh, bfl, biasp, bufA);
    conv_mfma<<<dim3(3, 3, 256), 256, 0, stream>>>(bufA, bufB, bfp,
                                                   biasp + 16, 0);   // conv3
    conv_mfma<<<dim3(3, 3, 256), 256, 0, stream>>>(bufB, bufA, bfp + 448 * 8,
                                                   biasp + 32, 1);   // conv4+relu
    mlp_kernel<<<1152, 256, 0, stream>>>(bufA, W1, b1, W2, b2, W3, mv, part2);
    reduce2_kernel<<<1, 256, 0, stream>>>(part2, ab, (float*)d_out);
}

// Round 10
// 201.043 us; speedup vs baseline: 1.1500x; 1.1500x over previous
//
#include <hip/hip_runtime.h>
#include <math.h>

typedef unsigned short ushort;
typedef unsigned int uint;
typedef __attribute__((ext_vector_type(8))) short bf16x8;
typedef __attribute__((ext_vector_type(8))) ushort ushort8;
typedef __attribute__((ext_vector_type(4))) float f32x4;

// ws layout (float offsets)
#define WT1_OFF   0          // 200 f   conv1 weights [tap][co]
#define MV_OFF    256        // 1152 f  mask vector
#define BIAS_OFF  1536       // 48 f    padded biases (conv2/3/4)
#define BFH_OFF   1600       // hi B-frags (3 convs): 3*7*64*8 ushort = 5376 f
#define BFL_OFF   6976       // lo B-frags: 5376 f
#define BFP_OFF   12352      // packed [bh|bl] B-frags for conv3/4: 2*448*8 ush = 3584 f
#define BUFA_OFF  16384      // activation buffer A: hi plane + lo plane
#define PLANE_U   9437184    // ushorts per plane (256*48*96*8)
#define BUFB_OFF  (BUFA_OFF + PLANE_U)
#define PART2_OFF (BUFB_OFF + PLANE_U)        // 48*256 f (atomic partials)

__device__ __forceinline__ ushort f2bf(float f) {      // RTNE fp32->bf16
    union { float f; uint u; } a; a.f = f;
    uint u = a.u;
    return (ushort)((u + 0x7FFFu + ((u >> 16) & 1u)) >> 16);
}
__device__ __forceinline__ float bf2f(ushort s) {
    union { uint u; float f; } a; a.u = ((uint)s) << 16; return a.f;
}
__device__ __forceinline__ void split_bf(float v, ushort& h, ushort& l) {
    h = f2bf(v);
    l = f2bf(v - bf2f(h));
}

// ---------------- K0: weights/mask/bias/B-frag precompute + part2 zero ---
__global__ void prep_kernel(const float* __restrict__ c1w, const float* __restrict__ c2w,
                            const float* __restrict__ c3w, const float* __restrict__ c4w,
                            const float* __restrict__ c2b, const float* __restrict__ c3b,
                            const float* __restrict__ c4b,
                            const float* __restrict__ mask, float* __restrict__ ws) {
    int idx = blockIdx.x * blockDim.x + threadIdx.x;
    if (idx < 200) {                       // conv1 weights -> [tap][co]
        int co = idx & 7, rest = idx >> 3;
        int dx = rest % 5, dy = rest / 5;
        ws[WT1_OFF + idx] = c1w[co * 25 + dy * 5 + dx];
    }
    if (idx < 1152) {
        int i = idx / 48, j = idx % 48;
        ws[MV_OFF + idx] = (mask[i * 8 * 384 + j * 8] > 0.5f) ? 1.0f : 0.0f;
    }
    if (idx < 48) {                        // padded biases
        int c = idx >> 4, co = idx & 15;
        const float* b = (c == 0) ? c2b : (c == 1) ? c3b : c4b;
        ws[BIAS_OFF + idx] = (co < 8) ? b[co] : 0.f;
    }
    if (idx < 1344) {                      // separate hi/lo B-frags (k1 uses conv2's)
        int c = idx / 448, rem = idx % 448;
        int g = rem >> 6, l = rem & 63;
        int tg = l >> 4, co16 = l & 15;
        int tap = g * 4 + tg;
        const float* wsrc = (c == 0) ? c2w : (c == 1) ? c3w : c4w;
        ushort* bh = (ushort*)(ws + BFH_OFF) + (size_t)idx * 8;
        ushort* bl = (ushort*)(ws + BFL_OFF) + (size_t)idx * 8;
#pragma unroll
        for (int j = 0; j < 8; ++j) {      // j = ci
            float v = 0.f;
            if (tap < 25 && co16 < 8)
                v = wsrc[((co16 * 8 + j) * 5 + tap / 5) * 5 + (tap % 5)];
            ushort h, lo; split_bf(v, h, lo);
            bh[j] = h; bl[j] = lo;
        }
    }
    if (idx < 896) {                       // packed [bh|bl] frags for conv3/conv4
        int c = idx / 448 + 1, rem = idx % 448;
        int g = rem >> 6, l = rem & 63;
        int tg = l >> 4, co16 = l & 15;
        int co = co16 & 7;
        int tap = g * 4 + tg;
        const float* wsrc = (c == 1) ? c3w : c4w;
        ushort* dst = (ushort*)(ws + BFP_OFF) + (size_t)idx * 8;
#pragma unroll
        for (int j = 0; j < 8; ++j) {
            float v = 0.f;
            if (tap < 25)
                v = wsrc[((co * 8 + j) * 5 + tap / 5) * 5 + (tap % 5)];
            ushort h, lo; split_bf(v, h, lo);
            dst[j] = (co16 < 8) ? h : lo;
        }
    }
    if (idx < 48 * 256)                    // zero atomic partial buffer
        ws[PART2_OFF + idx] = 0.f;
}

// ---------------- K1: ds + conv1(VALU) + conv2(3-MFMA split) + relu + pool
// Tile: 16 conv2-rows x 64 cols -> pooled 8x32. 4 waves; wave w rows 4w..4w+3.
// LDS 51.7 KB -> 3 blocks/CU (xdbuf overlaid with pooled bounce buffers).
// conv1 = r7's per-pixel form: 1360 units/block (5.3 rounds, balanced),
// FMA critical path 1200/thread. r8's 4-row strips (340 units, 1600 FMA path)
// regressed 55us -- granularity beats read-sharing here.
__global__ __launch_bounds__(256) void k1_fused(
        const float* __restrict__ x, const float* __restrict__ wt1,
        const float* __restrict__ c1b,
        const ushort* __restrict__ bfh, const ushort* __restrict__ bfl,
        const float* __restrict__ biaspad, ushort* __restrict__ z2) {
    __shared__ __align__(16) char smem0[8192];          // xdbuf | z2 bounce
    __shared__ ushort z1h[20 * 68 * 8];                 // 21,760 B
    __shared__ ushort z1l[20 * 68 * 8];                 // 21,760 B
    float (*xdbuf)[72] = reinterpret_cast<float(*)[72]>(smem0);   // 24x72 f32
    ushort* z2bh = (ushort*)smem0;                      // 8x32x8 (xdbuf dead by then)
    ushort* z2bl = (ushort*)(smem0 + 4096);
    const int rt = blockIdx.x, ct = blockIdx.y, b = blockIdx.z;
    const int tid = threadIdx.x;
    const int ry0 = rt * 16, cx0 = ct * 64;

    // phase 0: 2x2 avg downsample into xdbuf (fp32)
    for (int i = tid; i < 24 * 36; i += 256) {
        int pr = i / 36, pj = i % 36;
        int gy = ry0 - 4 + pr, gx = cx0 - 4 + 2 * pj;
        float v0 = 0.f, v1 = 0.f;
        if (gy >= 0 && gy < 96 && gx >= 0 && gx < 192) {
            const float* p = x + (size_t)b * (192 * 384) + (2 * gy) * 384 + 2 * gx;
            float4 a = *(const float4*)p;
            float4 c = *(const float4*)(p + 384);
            v0 = (a.x + a.y + c.x + c.y) * 0.25f;
            v1 = (a.z + a.w + c.z + c.w) * 0.25f;
        }
        xdbuf[pr][2 * pj]     = v0;
        xdbuf[pr][2 * pj + 1] = v1;
    }
    __syncthreads();

    // phase 1: conv1 -> split bf16 z1 planes (1 px per unit); OOB -> 0
    for (int i = tid; i < 20 * 68; i += 256) {
        int iy = i / 68, ix = i % 68;
        int gy = ry0 - 2 + iy, gx = cx0 - 2 + ix;
        float acc[8];
        if (gy >= 0 && gy < 96 && gx >= 0 && gx < 192) {
#pragma unroll
            for (int co = 0; co < 8; ++co) acc[co] = c1b[co];
#pragma unroll
            for (int dy = 0; dy < 5; ++dy)
#pragma unroll
                for (int dx = 0; dx < 5; ++dx) {
                    float v = xdbuf[iy + dy][ix + dx];
#pragma unroll
                    for (int co = 0; co < 8; ++co)
                        acc[co] = fmaf(v, wt1[(dy * 5 + dx) * 8 + co], acc[co]);
                }
        } else {
#pragma unroll
            for (int co = 0; co < 8; ++co) acc[co] = 0.f;
        }
        ushort8 uh, ul;
#pragma unroll
        for (int co = 0; co < 8; ++co) {
            ushort h, lo; split_bf(acc[co], h, lo);
            uh[co] = h; ul[co] = lo;
        }
        *(ushort8*)&z1h[i * 8] = uh;
        *(ushort8*)&z1l[i * 8] = ul;
    }
    __syncthreads();

    // phase 2: conv2 via 3-term split MFMA (all into one acc), + bias, relu, pool
    const int lane = tid & 63, w = tid >> 6;
    const int p = lane & 15, tg = lane >> 4;
    bf16x8 bwh[7], bwl[7];
#pragma unroll
    for (int g = 0; g < 7; ++g) {
        bwh[g] = *(const bf16x8*)(bfh + (size_t)(g * 64 + lane) * 8);
        bwl[g] = *(const bf16x8*)(bfl + (size_t)(g * 64 + lane) * 8);
    }
    const float bias = biaspad[lane & 15];
    int off[7];
#pragma unroll
    for (int g = 0; g < 7; ++g) {
        int t = g * 4 + tg; t = (t > 24) ? 24 : t;   // pad taps: zero weights
        off[g] = ((t / 5) * 68 + (t % 5)) * 8;
    }
    float stash[4][2];
#pragma unroll
    for (int rl = 0; rl < 4; ++rl) {
        const int r = 4 * w + rl;
#pragma unroll
        for (int cg = 0; cg < 4; ++cg) {
            f32x4 acc = {0.f, 0.f, 0.f, 0.f};
            const int base = (r * 68 + cg * 16 + p) * 8;
#pragma unroll
            for (int g = 0; g < 7; ++g) {
                bf16x8 ah = *(const bf16x8*)&z1h[base + off[g]];
                bf16x8 al = *(const bf16x8*)&z1l[base + off[g]];
                acc = __builtin_amdgcn_mfma_f32_16x16x32_bf16(ah, bwh[g], acc, 0, 0, 0);
                acc = __builtin_amdgcn_mfma_f32_16x16x32_bf16(ah, bwl[g], acc, 0, 0, 0);
                acc = __builtin_amdgcn_mfma_f32_16x16x32_bf16(al, bwh[g], acc, 0, 0, 0);
            }
            // C: col(lane&15)=co, row=tg*4+i=pixel. relu(max) + col-pair pool
            float p0 = fmaxf(fmaxf(acc[0], acc[1]) + bias, 0.f);
            float p1 = fmaxf(fmaxf(acc[2], acc[3]) + bias, 0.f);
            if ((rl & 1) == 0) {
                stash[cg][0] = p0; stash[cg][1] = p1;
            } else {
                p0 = fmaxf(p0, stash[cg][0]);
                p1 = fmaxf(p1, stash[cg][1]);
                if ((lane & 15) < 8) {
                    int pr = 2 * w + (rl >> 1);
                    int pc = cg * 8 + tg * 2;
                    ushort h0, l0, h1, l1;
                    split_bf(p0, h0, l0); split_bf(p1, h1, l1);
                    z2bh[(pr * 32 + pc) * 8 + (lane & 15)]     = h0;
                    z2bl[(pr * 32 + pc) * 8 + (lane & 15)]     = l0;
                    z2bh[(pr * 32 + pc + 1) * 8 + (lane & 15)] = h1;
                    z2bl[(pr * 32 + pc + 1) * 8 + (lane & 15)] = l1;
                }
            }
        }
    }
    __syncthreads();
    // cooperative pooled-tile store (8x32 px, 16B per plane)
    {
        int prr = tid >> 5, pcc = tid & 31;
        size_t gidx = ((size_t)(b * 48 + rt * 8 + prr) * 96 + ct * 32 + pcc) * 8;
        *(ushort8*)(z2 + gidx)           = *(const ushort8*)&z2bh[(prr * 32 + pcc) * 8];
        *(ushort8*)(z2 + PLANE_U + gidx) = *(const ushort8*)&z2bl[(prr * 32 + pcc) * 8];
    }
}

// ---------------- K2/K3: 8->8 conv via N-packed split MFMA ---------------
// Tile: 16 rows x 32 cols. LDS 39.4 KB -> 4 blocks/CU.
__global__ __launch_bounds__(256) void conv_mfma(
        const ushort* __restrict__ in, ushort* __restrict__ out,
        const ushort* __restrict__ bfrag, const float* __restrict__ biaspad,
        int do_relu) {
    __shared__ ushort inh[20 * 36 * 8];       // 11,520 B
    __shared__ ushort inl[20 * 36 * 8];       // 11,520 B
    __shared__ ushort outh[16 * 32 * 8];      // 8,192 B
    __shared__ ushort outl[16 * 32 * 8];      // 8,192 B
    const int rt = blockIdx.x, ctile = blockIdx.y, b = blockIdx.z;
    const int ry0 = rt * 16, cx0 = ctile * 32;
    const int tid = threadIdx.x;

    // stage 20x36 px (16B per plane), zero-padded
    for (int u = tid; u < 20 * 36; u += 256) {
        int r = u / 36, col = u % 36;
        int gy = ry0 - 2 + r, gc = cx0 - 2 + col;
        ushort8 vh = {0, 0, 0, 0, 0, 0, 0, 0};
        ushort8 vl = vh;
        if (gy >= 0 && gy < 48 && gc >= 0 && gc < 96) {
            size_t gidx = ((size_t)(b * 48 + gy) * 96 + gc) * 8;
            vh = *(const ushort8*)(in + gidx);
            vl = *(const ushort8*)(in + PLANE_U + gidx);
        }
        *(ushort8*)&inh[u * 8] = vh;
        *(ushort8*)&inl[u * 8] = vl;
    }
    __syncthreads();

    const int lane = tid & 63, w = tid >> 6;
    const int p = lane & 15, tg = lane >> 4;
    bf16x8 bw[7];
#pragma unroll
    for (int g = 0; g < 7; ++g)
        bw[g] = *(const bf16x8*)(bfrag + (size_t)(g * 64 + lane) * 8);
    const float bias = biaspad[lane & 15];
    int off[7];
#pragma unroll
    for (int g = 0; g < 7; ++g) {
        int t = g * 4 + tg; t = (t > 24) ? 24 : t;
        off[g] = ((t / 5) * 36 + (t % 5)) * 8;
    }
#pragma unroll
    for (int rl = 0; rl < 4; ++rl) {
        const int r = 4 * w + rl;
#pragma unroll
        for (int cg = 0; cg < 2; ++cg) {
            f32x4 a1 = {0.f, 0.f, 0.f, 0.f};
            f32x4 a2 = {0.f, 0.f, 0.f, 0.f};
            const int base = (r * 36 + cg * 16 + p) * 8;
#pragma unroll
            for (int g = 0; g < 7; ++g) {
                bf16x8 ah = *(const bf16x8*)&inh[base + off[g]];
                bf16x8 al = *(const bf16x8*)&inl[base + off[g]];
                a1 = __builtin_amdgcn_mfma_f32_16x16x32_bf16(ah, bw[g], a1, 0, 0, 0);
                a2 = __builtin_amdgcn_mfma_f32_16x16x32_bf16(al, bw[g], a2, 0, 0, 0);
            }
            f32x4 s = a1 + a2;
            float tot[4];
#pragma unroll
            for (int i = 0; i < 4; ++i)
                tot[i] = s[i] + __shfl_xor(s[i], 8);
            if ((lane & 15) < 8) {
#pragma unroll
                for (int i = 0; i < 4; ++i) {
                    float v = tot[i] + bias;
                    if (do_relu) v = fmaxf(v, 0.f);
                    int px = r * 32 + cg * 16 + tg * 4 + i;
                    ushort h, lo; split_bf(v, h, lo);
                    outh[px * 8 + (lane & 15)] = h;
                    outl[px * 8 + (lane & 15)] = lo;
                }
            }
        }
    }
    __syncthreads();
    for (int u = tid; u < 16 * 32; u += 256) {
        int row = u / 32, col = u % 32;
        size_t gidx = ((size_t)(b * 48 + ry0 + row) * 96 + cx0 + col) * 8;
        *(ushort8*)(out + gidx)           = *(const ushort8*)&outh[u * 8];
        *(ushort8*)(out + PLANE_U + gidx) = *(const ushort8*)&outl[u * 8];
    }
}

// ---------------- K4: per-feature MLP; atomic partial into part2 ---------
__global__ __launch_bounds__(256) void mlp_kernel(
        const ushort* __restrict__ z4, const float* __restrict__ W1,
        const float* __restrict__ b1, const float* __restrict__ W2,
        const float* __restrict__ b2, const float* __restrict__ W3,
        const float* __restrict__ mv, float* __restrict__ part2) {
    const int f = blockIdx.x;
    const int bb = threadIdx.x;
    if (mv[f] == 0.f) return;
    const int y = f / 48, xcol = f % 48;
    size_t s0i = (((size_t)bb * 48 + 2 * y) * 96 + 2 * xcol) * 8;
    ushort8 ah0 = *(const ushort8*)(z4 + s0i);
    ushort8 ah1 = *(const ushort8*)(z4 + s0i + 8);
    ushort8 ch0 = *(const ushort8*)(z4 + s0i + 96 * 8);
    ushort8 ch1 = *(const ushort8*)(z4 + s0i + 96 * 8 + 8);
    ushort8 al0 = *(const ushort8*)(z4 + PLANE_U + s0i);
    ushort8 al1 = *(const ushort8*)(z4 + PLANE_U + s0i + 8);
    ushort8 cl0 = *(const ushort8*)(z4 + PLANE_U + s0i + 96 * 8);
    ushort8 cl1 = *(const ushort8*)(z4 + PLANE_U + s0i + 96 * 8 + 8);
    float h[8];
#pragma unroll
    for (int c = 0; c < 8; ++c) {
        float v00 = bf2f(ah0[c]) + bf2f(al0[c]);
        float v01 = bf2f(ah1[c]) + bf2f(al1[c]);
        float v10 = bf2f(ch0[c]) + bf2f(cl0[c]);
        float v11 = bf2f(ch1[c]) + bf2f(cl1[c]);
        h[c] = fmaxf(fmaxf(v00, v01), fmaxf(v10, v11));
    }

    const float* w1p = W1 + (size_t)f * 8 * 32;
    const float* b1p = b1 + (size_t)f * 32;
    float t1[32];
#pragma unroll
    for (int j = 0; j < 32; ++j) t1[j] = b1p[j];
    for (int c = 0; c < 8; ++c) {
        float hv = h[c];
        const float* wp = w1p + c * 32;
#pragma unroll
        for (int j = 0; j < 32; ++j) t1[j] = fmaf(hv, wp[j], t1[j]);
    }
#pragma unroll
    for (int j = 0; j < 32; ++j) t1[j] = fmaxf(t1[j], 0.f);

    const float* w2p = W2 + (size_t)f * 32 * 32;
    const float* b2p = b2 + (size_t)f * 32;
    float t2[32];
#pragma unroll
    for (int g = 0; g < 32; ++g) t2[g] = b2p[g];
    for (int j = 0; j < 32; ++j) {
        float tv = t1[j];
        const float* wp = w2p + j * 32;
#pragma unroll
        for (int g = 0; g < 32; ++g) t2[g] = fmaf(tv, wp[g], t2[g]);
    }
    const float* w3p = W3 + (size_t)f * 32;
    float s = 0.f;
#pragma unroll
    for (int g = 0; g < 32; ++g) s = fmaf(fmaxf(t2[g], 0.f), w3p[g], s);
    atomicAdd(&part2[(size_t)(f / 24) * 256 + bb], s);
}

// ---------------- K5: final reduce + bias + sigmoid ----------------------
__global__ void reduce2_kernel(const float* __restrict__ part2, const float* __restrict__ ab,
                               float* __restrict__ out) {
    int bb = threadIdx.x;
    float s = 0.f;
    for (int k = 0; k < 48; ++k) s += part2[(size_t)k * 256 + bb];
    s += ab[0];
    out[bb] = 1.f / (1.f + expf(-s));
}

extern "C" void kernel_launch(void* const* d_in, const int* in_sizes, int n_in,
                              void* d_out, int out_size, void* d_ws, size_t ws_size,
                              hipStream_t stream) {
    const float* x    = (const float*)d_in[0];
    const float* mask = (const float*)d_in[1];
    const float* c1w  = (const float*)d_in[2];
    const float* c1b  = (const float*)d_in[3];
    const float* c2w  = (const float*)d_in[4];
    const float* c2b  = (const float*)d_in[5];
    const float* c3w  = (const float*)d_in[6];
    const float* c3b  = (const float*)d_in[7];
    const float* c4w  = (const float*)d_in[8];
    const float* c4b  = (const float*)d_in[9];
    const float* W1   = (const float*)d_in[10];
    const float* b1   = (const float*)d_in[11];
    const float* W2   = (const float*)d_in[12];
    const float* b2   = (const float*)d_in[13];
    const float* W3   = (const float*)d_in[14];
    const float* ab   = (const float*)d_in[15];
    float* ws = (float*)d_ws;

    float*  wt1   = ws + WT1_OFF;
    float*  mv    = ws + MV_OFF;
    float*  biasp = ws + BIAS_OFF;
    ushort* bfh   = (ushort*)(ws + BFH_OFF);
    ushort* bfl   = (ushort*)(ws + BFL_OFF);
    ushort* bfp   = (ushort*)(ws + BFP_OFF);
    ushort* bufA  = (ushort*)(ws + BUFA_OFF);  // z2, later z4
    ushort* bufB  = (ushort*)(ws + BUFB_OFF);  // z3
    float*  part2 = ws + PART2_OFF;

    prep_kernel<<<48, 256, 0, stream>>>(c1w, c2w, c3w, c4w, c2b, c3b, c4b, mask, ws);
    k1_fused<<<dim3(6, 3, 256), 256, 0, stream>>>(x, wt1, c1b, bfh, bfl, biasp, bufA);
    conv_mfma<<<dim3(3, 3, 256), 256, 0, stream>>>(bufA, bufB, bfp,
                                                   biasp + 16, 0);   // conv3
    conv_mfma<<<dim3(3, 3, 256), 256, 0, stream>>>(bufB, bufA, bfp + 448 * 8,
                                                   biasp + 32, 1);   // conv4+relu
    mlp_kernel<<<1152, 256, 0, stream>>>(bufA, W1, b1, W2, b2, W3, mv, part2);
    reduce2_kernel<<<1, 256, 0, stream>>>(part2, ab, (float*)d_out);
}

// Round 11
// 194.274 us; speedup vs baseline: 1.1901x; 1.0348x over previous
//
#include <hip/hip_runtime.h>
#include <math.h>

typedef unsigned short ushort;
typedef unsigned int uint;
typedef __attribute__((ext_vector_type(8))) short bf16x8;
typedef __attribute__((ext_vector_type(8))) ushort ushort8;
typedef __attribute__((ext_vector_type(4))) float f32x4;

// ws layout (float offsets)
#define WT1_OFF   0          // 200 f   conv1 weights [tap][co]
#define MV_OFF    256        // 1152 f  mask vector
#define BIAS_OFF  1536       // 48 f    padded biases (conv2/3/4)
#define BFH_OFF   1600       // hi B-frags (3 convs): 3*7*64*8 ushort = 5376 f
#define BFL_OFF   6976       // lo B-frags: 5376 f
#define BFP_OFF   12352      // packed [bh|bl] B-frags for conv3/4: 2*448*8 ush = 3584 f
#define BUFA_OFF  16384      // activation buffer A: hi plane + lo plane
#define PLANE_U   9437184    // ushorts per plane (256*48*96*8)
#define BUFB_OFF  (BUFA_OFF + PLANE_U)
#define PART2_OFF (BUFB_OFF + PLANE_U)        // 48*256 f (atomic partials)

__device__ __forceinline__ ushort f2bf(float f) {      // RTNE fp32->bf16
    union { float f; uint u; } a; a.f = f;
    uint u = a.u;
    return (ushort)((u + 0x7FFFu + ((u >> 16) & 1u)) >> 16);
}
__device__ __forceinline__ float bf2f(ushort s) {
    union { uint u; float f; } a; a.u = ((uint)s) << 16; return a.f;
}
__device__ __forceinline__ void split_bf(float v, ushort& h, ushort& l) {
    h = f2bf(v);
    l = f2bf(v - bf2f(h));
}

// ---------------- K0: weights/mask/bias/B-frag precompute + part2 zero ---
__global__ void prep_kernel(const float* __restrict__ c1w, const float* __restrict__ c2w,
                            const float* __restrict__ c3w, const float* __restrict__ c4w,
                            const float* __restrict__ c2b, const float* __restrict__ c3b,
                            const float* __restrict__ c4b,
                            const float* __restrict__ mask, float* __restrict__ ws) {
    int idx = blockIdx.x * blockDim.x + threadIdx.x;
    if (idx < 200) {                       // conv1 weights -> [tap][co]
        int co = idx & 7, rest = idx >> 3;
        int dx = rest % 5, dy = rest / 5;
        ws[WT1_OFF + idx] = c1w[co * 25 + dy * 5 + dx];
    }
    if (idx < 1152) {
        int i = idx / 48, j = idx % 48;
        ws[MV_OFF + idx] = (mask[i * 8 * 384 + j * 8] > 0.5f) ? 1.0f : 0.0f;
    }
    if (idx < 48) {                        // padded biases
        int c = idx >> 4, co = idx & 15;
        const float* b = (c == 0) ? c2b : (c == 1) ? c3b : c4b;
        ws[BIAS_OFF + idx] = (co < 8) ? b[co] : 0.f;
    }
    if (idx < 1344) {                      // separate hi/lo B-frags (k1 uses conv2's)
        int c = idx / 448, rem = idx % 448;
        int g = rem >> 6, l = rem & 63;
        int tg = l >> 4, co16 = l & 15;
        int tap = g * 4 + tg;
        const float* wsrc = (c == 0) ? c2w : (c == 1) ? c3w : c4w;
        ushort* bh = (ushort*)(ws + BFH_OFF) + (size_t)idx * 8;
        ushort* bl = (ushort*)(ws + BFL_OFF) + (size_t)idx * 8;
#pragma unroll
        for (int j = 0; j < 8; ++j) {      // j = ci
            float v = 0.f;
            if (tap < 25 && co16 < 8)
                v = wsrc[((co16 * 8 + j) * 5 + tap / 5) * 5 + (tap % 5)];
            ushort h, lo; split_bf(v, h, lo);
            bh[j] = h; bl[j] = lo;
        }
    }
    if (idx < 896) {                       // packed [bh|bl] frags for conv3/conv4
        int c = idx / 448 + 1, rem = idx % 448;
        int g = rem >> 6, l = rem & 63;
        int tg = l >> 4, co16 = l & 15;
        int co = co16 & 7;
        int tap = g * 4 + tg;
        const float* wsrc = (c == 1) ? c3w : c4w;
        ushort* dst = (ushort*)(ws + BFP_OFF) + (size_t)idx * 8;
#pragma unroll
        for (int j = 0; j < 8; ++j) {
            float v = 0.f;
            if (tap < 25)
                v = wsrc[((co * 8 + j) * 5 + tap / 5) * 5 + (tap % 5)];
            ushort h, lo; split_bf(v, h, lo);
            dst[j] = (co16 < 8) ? h : lo;
        }
    }
    if (idx < 48 * 256)                    // zero atomic partial buffer
        ws[PART2_OFF + idx] = 0.f;
}

// ---------------- K1: ds + conv1(VALU) + conv2(3-MFMA split) + relu + pool
// Tile: 16 conv2-rows x 64 cols -> pooled 8x32. NOW 512 threads = 8 waves;
// wave w owns rows {2w, 2w+1}. LDS 51.7 KB -> 3 blocks/CU x 8 waves
// = 24 waves/CU (was 12) -- pure occupancy boost, identical work/LDS traffic.
__global__ __launch_bounds__(512) void k1_fused(
        const float* __restrict__ x, const float* __restrict__ wt1,
        const float* __restrict__ c1b,
        const ushort* __restrict__ bfh, const ushort* __restrict__ bfl,
        const float* __restrict__ biaspad, ushort* __restrict__ z2) {
    __shared__ __align__(16) char smem0[8192];          // xdbuf | z2 bounce
    __shared__ ushort z1h[20 * 68 * 8];                 // 21,760 B
    __shared__ ushort z1l[20 * 68 * 8];                 // 21,760 B
    float (*xdbuf)[72] = reinterpret_cast<float(*)[72]>(smem0);   // 24x72 f32
    ushort* z2bh = (ushort*)smem0;                      // 8x32x8 (xdbuf dead by then)
    ushort* z2bl = (ushort*)(smem0 + 4096);
    const int rt = blockIdx.x, ct = blockIdx.y, b = blockIdx.z;
    const int tid = threadIdx.x;
    const int ry0 = rt * 16, cx0 = ct * 64;

    // phase 0: 2x2 avg downsample into xdbuf (fp32)
    for (int i = tid; i < 24 * 36; i += 512) {
        int pr = i / 36, pj = i % 36;
        int gy = ry0 - 4 + pr, gx = cx0 - 4 + 2 * pj;
        float v0 = 0.f, v1 = 0.f;
        if (gy >= 0 && gy < 96 && gx >= 0 && gx < 192) {
            const float* p = x + (size_t)b * (192 * 384) + (2 * gy) * 384 + 2 * gx;
            float4 a = *(const float4*)p;
            float4 c = *(const float4*)(p + 384);
            v0 = (a.x + a.y + c.x + c.y) * 0.25f;
            v1 = (a.z + a.w + c.z + c.w) * 0.25f;
        }
        xdbuf[pr][2 * pj]     = v0;
        xdbuf[pr][2 * pj + 1] = v1;
    }
    __syncthreads();

    // phase 1: conv1 -> split bf16 z1 planes (1 px per unit); OOB -> 0
    for (int i = tid; i < 20 * 68; i += 512) {
        int iy = i / 68, ix = i % 68;
        int gy = ry0 - 2 + iy, gx = cx0 - 2 + ix;
        float acc[8];
        if (gy >= 0 && gy < 96 && gx >= 0 && gx < 192) {
#pragma unroll
            for (int co = 0; co < 8; ++co) acc[co] = c1b[co];
#pragma unroll
            for (int dy = 0; dy < 5; ++dy)
#pragma unroll
                for (int dx = 0; dx < 5; ++dx) {
                    float v = xdbuf[iy + dy][ix + dx];
#pragma unroll
                    for (int co = 0; co < 8; ++co)
                        acc[co] = fmaf(v, wt1[(dy * 5 + dx) * 8 + co], acc[co]);
                }
        } else {
#pragma unroll
            for (int co = 0; co < 8; ++co) acc[co] = 0.f;
        }
        ushort8 uh, ul;
#pragma unroll
        for (int co = 0; co < 8; ++co) {
            ushort h, lo; split_bf(acc[co], h, lo);
            uh[co] = h; ul[co] = lo;
        }
        *(ushort8*)&z1h[i * 8] = uh;
        *(ushort8*)&z1l[i * 8] = ul;
    }
    __syncthreads();

    // phase 2: conv2 via 3-term split MFMA; wave w rows {2w, 2w+1}
    const int lane = tid & 63, w = tid >> 6;
    const int p = lane & 15, tg = lane >> 4;
    bf16x8 bwh[7], bwl[7];
#pragma unroll
    for (int g = 0; g < 7; ++g) {
        bwh[g] = *(const bf16x8*)(bfh + (size_t)(g * 64 + lane) * 8);
        bwl[g] = *(const bf16x8*)(bfl + (size_t)(g * 64 + lane) * 8);
    }
    const float bias = biaspad[lane & 15];
    int off[7];
#pragma unroll
    for (int g = 0; g < 7; ++g) {
        int t = g * 4 + tg; t = (t > 24) ? 24 : t;   // pad taps: zero weights
        off[g] = ((t / 5) * 68 + (t % 5)) * 8;
    }
    float stash[4][2];
#pragma unroll
    for (int rl = 0; rl < 2; ++rl) {
        const int r = 2 * w + rl;
#pragma unroll
        for (int cg = 0; cg < 4; ++cg) {
            f32x4 acc = {0.f, 0.f, 0.f, 0.f};
            const int base = (r * 68 + cg * 16 + p) * 8;
#pragma unroll
            for (int g = 0; g < 7; ++g) {
                bf16x8 ah = *(const bf16x8*)&z1h[base + off[g]];
                bf16x8 al = *(const bf16x8*)&z1l[base + off[g]];
                acc = __builtin_amdgcn_mfma_f32_16x16x32_bf16(ah, bwh[g], acc, 0, 0, 0);
                acc = __builtin_amdgcn_mfma_f32_16x16x32_bf16(ah, bwl[g], acc, 0, 0, 0);
                acc = __builtin_amdgcn_mfma_f32_16x16x32_bf16(al, bwh[g], acc, 0, 0, 0);
            }
            // C: col(lane&15)=co, row=tg*4+i=pixel. relu(max) + col-pair pool
            float p0 = fmaxf(fmaxf(acc[0], acc[1]) + bias, 0.f);
            float p1 = fmaxf(fmaxf(acc[2], acc[3]) + bias, 0.f);
            if (rl == 0) {
                stash[cg][0] = p0; stash[cg][1] = p1;
            } else {
                p0 = fmaxf(p0, stash[cg][0]);
                p1 = fmaxf(p1, stash[cg][1]);
                if ((lane & 15) < 8) {
                    int pr = w;
                    int pc = cg * 8 + tg * 2;
                    ushort h0, l0, h1, l1;
                    split_bf(p0, h0, l0); split_bf(p1, h1, l1);
                    z2bh[(pr * 32 + pc) * 8 + (lane & 15)]     = h0;
                    z2bl[(pr * 32 + pc) * 8 + (lane & 15)]     = l0;
                    z2bh[(pr * 32 + pc + 1) * 8 + (lane & 15)] = h1;
                    z2bl[(pr * 32 + pc + 1) * 8 + (lane & 15)] = l1;
                }
            }
        }
    }
    __syncthreads();
    // cooperative pooled-tile store (8x32 px, 16B per plane)
    if (tid < 256) {
        int prr = tid >> 5, pcc = tid & 31;
        size_t gidx = ((size_t)(b * 48 + rt * 8 + prr) * 96 + ct * 32 + pcc) * 8;
        *(ushort8*)(z2 + gidx)           = *(const ushort8*)&z2bh[(prr * 32 + pcc) * 8];
        *(ushort8*)(z2 + PLANE_U + gidx) = *(const ushort8*)&z2bl[(prr * 32 + pcc) * 8];
    }
}

// ---------------- K2/K3: 8->8 conv via N-packed split MFMA ---------------
// Tile: 16 rows x 32 cols, 512 threads = 8 waves (wave w rows {2w,2w+1}).
// LDS 39.4 KB -> 4 blocks/CU x 8 waves = 32 waves/CU.
__global__ __launch_bounds__(512) void conv_mfma(
        const ushort* __restrict__ in, ushort* __restrict__ out,
        const ushort* __restrict__ bfrag, const float* __restrict__ biaspad,
        int do_relu) {
    __shared__ ushort inh[20 * 36 * 8];       // 11,520 B
    __shared__ ushort inl[20 * 36 * 8];       // 11,520 B
    __shared__ ushort outh[16 * 32 * 8];      // 8,192 B
    __shared__ ushort outl[16 * 32 * 8];      // 8,192 B
    const int rt = blockIdx.x, ctile = blockIdx.y, b = blockIdx.z;
    const int ry0 = rt * 16, cx0 = ctile * 32;
    const int tid = threadIdx.x;

    // stage 20x36 px (16B per plane), zero-padded
    for (int u = tid; u < 20 * 36; u += 512) {
        int r = u / 36, col = u % 36;
        int gy = ry0 - 2 + r, gc = cx0 - 2 + col;
        ushort8 vh = {0, 0, 0, 0, 0, 0, 0, 0};
        ushort8 vl = vh;
        if (gy >= 0 && gy < 48 && gc >= 0 && gc < 96) {
            size_t gidx = ((size_t)(b * 48 + gy) * 96 + gc) * 8;
            vh = *(const ushort8*)(in + gidx);
            vl = *(const ushort8*)(in + PLANE_U + gidx);
        }
        *(ushort8*)&inh[u * 8] = vh;
        *(ushort8*)&inl[u * 8] = vl;
    }
    __syncthreads();

    const int lane = tid & 63, w = tid >> 6;
    const int p = lane & 15, tg = lane >> 4;
    bf16x8 bw[7];
#pragma unroll
    for (int g = 0; g < 7; ++g)
        bw[g] = *(const bf16x8*)(bfrag + (size_t)(g * 64 + lane) * 8);
    const float bias = biaspad[lane & 15];
    int off[7];
#pragma unroll
    for (int g = 0; g < 7; ++g) {
        int t = g * 4 + tg; t = (t > 24) ? 24 : t;
        off[g] = ((t / 5) * 36 + (t % 5)) * 8;
    }
#pragma unroll
    for (int rl = 0; rl < 2; ++rl) {
        const int r = 2 * w + rl;
#pragma unroll
        for (int cg = 0; cg < 2; ++cg) {
            f32x4 a1 = {0.f, 0.f, 0.f, 0.f};
            f32x4 a2 = {0.f, 0.f, 0.f, 0.f};
            const int base = (r * 36 + cg * 16 + p) * 8;
#pragma unroll
            for (int g = 0; g < 7; ++g) {
                bf16x8 ah = *(const bf16x8*)&inh[base + off[g]];
                bf16x8 al = *(const bf16x8*)&inl[base + off[g]];
                a1 = __builtin_amdgcn_mfma_f32_16x16x32_bf16(ah, bw[g], a1, 0, 0, 0);
                a2 = __builtin_amdgcn_mfma_f32_16x16x32_bf16(al, bw[g], a2, 0, 0, 0);
            }
            f32x4 s = a1 + a2;
            float tot[4];
#pragma unroll
            for (int i = 0; i < 4; ++i)
                tot[i] = s[i] + __shfl_xor(s[i], 8);
            if ((lane & 15) < 8) {
#pragma unroll
                for (int i = 0; i < 4; ++i) {
                    float v = tot[i] + bias;
                    if (do_relu) v = fmaxf(v, 0.f);
                    int px = r * 32 + cg * 16 + tg * 4 + i;
                    ushort h, lo; split_bf(v, h, lo);
                    outh[px * 8 + (lane & 15)] = h;
                    outl[px * 8 + (lane & 15)] = lo;
                }
            }
        }
    }
    __syncthreads();
    {
        int u = tid;                      // 16*32 = 512 px, one per thread
        int row = u / 32, col = u % 32;
        size_t gidx = ((size_t)(b * 48 + ry0 + row) * 96 + cx0 + col) * 8;
        *(ushort8*)(out + gidx)           = *(const ushort8*)&outh[u * 8];
        *(ushort8*)(out + PLANE_U + gidx) = *(const ushort8*)&outl[u * 8];
    }
}

// ---------------- K4: per-feature MLP; atomic partial into part2 ---------
__global__ __launch_bounds__(256) void mlp_kernel(
        const ushort* __restrict__ z4, const float* __restrict__ W1,
        const float* __restrict__ b1, const float* __restrict__ W2,
        const float* __restrict__ b2, const float* __restrict__ W3,
        const float* __restrict__ mv, float* __restrict__ part2) {
    const int f = blockIdx.x;
    const int bb = threadIdx.x;
    if (mv[f] == 0.f) return;
    const int y = f / 48, xcol = f % 48;
    size_t s0i = (((size_t)bb * 48 + 2 * y) * 96 + 2 * xcol) * 8;
    ushort8 ah0 = *(const ushort8*)(z4 + s0i);
    ushort8 ah1 = *(const ushort8*)(z4 + s0i + 8);
    ushort8 ch0 = *(const ushort8*)(z4 + s0i + 96 * 8);
    ushort8 ch1 = *(const ushort8*)(z4 + s0i + 96 * 8 + 8);
    ushort8 al0 = *(const ushort8*)(z4 + PLANE_U + s0i);
    ushort8 al1 = *(const ushort8*)(z4 + PLANE_U + s0i + 8);
    ushort8 cl0 = *(const ushort8*)(z4 + PLANE_U + s0i + 96 * 8);
    ushort8 cl1 = *(const ushort8*)(z4 + PLANE_U + s0i + 96 * 8 + 8);
    float h[8];
#pragma unroll
    for (int c = 0; c < 8; ++c) {
        float v00 = bf2f(ah0[c]) + bf2f(al0[c]);
        float v01 = bf2f(ah1[c]) + bf2f(al1[c]);
        float v10 = bf2f(ch0[c]) + bf2f(cl0[c]);
        float v11 = bf2f(ch1[c]) + bf2f(cl1[c]);
        h[c] = fmaxf(fmaxf(v00, v01), fmaxf(v10, v11));
    }

    const float* w1p = W1 + (size_t)f * 8 * 32;
    const float* b1p = b1 + (size_t)f * 32;
    float t1[32];
#pragma unroll
    for (int j = 0; j < 32; ++j) t1[j] = b1p[j];
    for (int c = 0; c < 8; ++c) {
        float hv = h[c];
        const float* wp = w1p + c * 32;
#pragma unroll
        for (int j = 0; j < 32; ++j) t1[j] = fmaf(hv, wp[j], t1[j]);
    }
#pragma unroll
    for (int j = 0; j < 32; ++j) t1[j] = fmaxf(t1[j], 0.f);

    const float* w2p = W2 + (size_t)f * 32 * 32;
    const float* b2p = b2 + (size_t)f * 32;
    float t2[32];
#pragma unroll
    for (int g = 0; g < 32; ++g) t2[g] = b2p[g];
    for (int j = 0; j < 32; ++j) {
        float tv = t1[j];
        const float* wp = w2p + j * 32;
#pragma unroll
        for (int g = 0; g < 32; ++g) t2[g] = fmaf(tv, wp[g], t2[g]);
    }
    const float* w3p = W3 + (size_t)f * 32;
    float s = 0.f;
#pragma unroll
    for (int g = 0; g < 32; ++g) s = fmaf(fmaxf(t2[g], 0.f), w3p[g], s);
    atomicAdd(&part2[(size_t)(f / 24) * 256 + bb], s);
}

// ---------------- K5: final reduce + bias + sigmoid ----------------------
__global__ void reduce2_kernel(const float* __restrict__ part2, const float* __restrict__ ab,
                               float* __restrict__ out) {
    int bb = threadIdx.x;
    float s = 0.f;
    for (int k = 0; k < 48; ++k) s += part2[(size_t)k * 256 + bb];
    s += ab[0];
    out[bb] = 1.f / (1.f + expf(-s));
}

extern "C" void kernel_launch(void* const* d_in, const int* in_sizes, int n_in,
                              void* d_out, int out_size, void* d_ws, size_t ws_size,
                              hipStream_t stream) {
    const float* x    = (const float*)d_in[0];
    const float* mask = (const float*)d_in[1];
    const float* c1w  = (const float*)d_in[2];
    const float* c1b  = (const float*)d_in[3];
    const float* c2w  = (const float*)d_in[4];
    const float* c2b  = (const float*)d_in[5];
    const float* c3w  = (const float*)d_in[6];
    const float* c3b  = (const float*)d_in[7];
    const float* c4w  = (const float*)d_in[8];
    const float* c4b  = (const float*)d_in[9];
    const float* W1   = (const float*)d_in[10];
    const float* b1   = (const float*)d_in[11];
    const float* W2   = (const float*)d_in[12];
    const float* b2   = (const float*)d_in[13];
    const float* W3   = (const float*)d_in[14];
    const float* ab   = (const float*)d_in[15];
    float* ws = (float*)d_ws;

    float*  wt1   = ws + WT1_OFF;
    float*  mv    = ws + MV_OFF;
    float*  biasp = ws + BIAS_OFF;
    ushort* bfh   = (ushort*)(ws + BFH_OFF);
    ushort* bfl   = (ushort*)(ws + BFL_OFF);
    ushort* bfp   = (ushort*)(ws + BFP_OFF);
    ushort* bufA  = (ushort*)(ws + BUFA_OFF);  // z2, later z4
    ushort* bufB  = (ushort*)(ws + BUFB_OFF);  // z3
    float*  part2 = ws + PART2_OFF;

    prep_kernel<<<48, 256, 0, stream>>>(c1w, c2w, c3w, c4w, c2b, c3b, c4b, mask, ws);
    k1_fused<<<dim3(6, 3, 256), 512, 0, stream>>>(x, wt1, c1b, bfh, bfl, biasp, bufA);
    conv_mfma<<<dim3(3, 3, 256), 512, 0, stream>>>(bufA, bufB, bfp,
                                                   biasp + 16, 0);   // conv3
    conv_mfma<<<dim3(3, 3, 256), 512, 0, stream>>>(bufB, bufA, bfp + 448 * 8,
                                                   biasp + 32, 1);   // conv4+relu
    mlp_kernel<<<1152, 256, 0, stream>>>(bufA, W1, b1, W2, b2, W3, mv, part2);
    reduce2_kernel<<<1, 256, 0, stream>>>(part2, ab, (float*)d_out);
}